// Round 8
// baseline (228.839 us; speedup 1.0000x reference)
//
#include <hip/hip_runtime.h>
#include <hip/hip_bf16.h>
#include <math.h>

#define BB 2
#define CC 128
#define HH 96
#define WW 96
#define HWX (HH*WW)        // 9216
#define KTOT (CC*9)        // 1152
#define OC 128
#define KHALF 576          // deform K split: 64 channels per half
#define ROWH 600           // 576 + 24 pad; 1200 B row stride (16B-aligned, 2-way-free banks)

#define NZERO (BB*21*HWX)  // 387072
#define NWREP (KTOT*24)    // 27648
#define NWBF  (KTOT*OC)    // 147456

typedef __attribute__((ext_vector_type(8))) __bf16 bf16x8;
typedef __attribute__((ext_vector_type(4))) float floatx4;

// ---------------- K0: fused prep — zero accumulators + wrep repack + conv_w->bf16 -----
__global__ __launch_bounds__(256) void prep_kernel(const float* __restrict__ cw,
                                                   const float* __restrict__ pw,
                                                   const float* __restrict__ aw,
                                                   float* __restrict__ offw,   // +adw contig
                                                   float* __restrict__ wrep,
                                                   __bf16* __restrict__ wbf)
{
    int t = blockIdx.x * 256 + threadIdx.x;
    if (t < NZERO) {
        offw[t] = 0.f;
    } else if (t < NZERO + NWREP) {
        int r = t - NZERO;
        int tapch = r / 24;
        int o = r - tapch * 24;
        float v = 0.f;
        if (o < 18)      v = pw[o * KTOT + tapch];
        else if (o < 21) v = aw[(o - 18) * KTOT + tapch];
        wrep[r] = v;
    } else if (t < NZERO + NWREP + NWBF) {
        int r = t - NZERO - NWREP;
        wbf[r] = (__bf16)cw[r];     // scalar stores (verified class)
    }
}

// ---------------- K1: offsets conv — 2 px/lane, 8x16 tile, all operands in LDS --------
// grid = BB*72*4 = 576, 512 thr = 8 waves x 4 channels. Raw sums via atomicAdd.
__global__ __launch_bounds__(512) void offsets_kernel(
    const float* __restrict__ x, const float* __restrict__ wrep,
    float* __restrict__ offw, float* __restrict__ adw)
{
    __shared__ float sm[12672];   // [0,5760): xs[32][10][18]; [5760,12672): wl[32*9*24]
                                  // reduce phase aliases [0,10752)
    int blk = blockIdx.x;
    int cq = blk & 3;
    int rest = blk >> 2;
    int b = rest / 72;
    int t2 = rest % 72;
    int ti = t2 / 6, tj = t2 % 6;
    int i0 = ti * 8, j0 = tj * 16;
    int tid = threadIdx.x;
    float* xs = sm;
    float* wl = sm + 5760;

    for (int idx = tid; idx < 5760; idx += 512) {
        int cl = idx / 180; int r = idx % 180; int u = r / 18, v = r % 18;
        int gi = i0 + u - 1, gj = j0 + v - 1;
        float val = 0.f;
        if (gi >= 0 && gi < HH && gj >= 0 && gj < WW)
            val = x[((b * CC + cq * 32 + cl) * HH + gi) * WW + gj];
        xs[idx] = val;
    }
    {   // weights: 32*9*24 = 6912 floats, coalesced float4
        const float4* src = (const float4*)(wrep + (size_t)(cq * 32) * 216);
        float4* dst = (float4*)wl;
        for (int idx = tid; idx < 1728; idx += 512) dst[idx] = src[idx];
    }
    __syncthreads();

    int wave = tid >> 6, lane = tid & 63;
    int pi = lane >> 3, pj = lane & 7;          // px0 = (pi,pj), px1 = (pi,pj+8)
    float acc[42];
#pragma unroll
    for (int o = 0; o < 42; ++o) acc[o] = 0.f;

    for (int cc = 0; cc < 4; ++cc) {
        int cl = wave * 4 + cc;
        const float* xr = &xs[cl * 180 + pi * 18 + pj];
        const float* wr = &wl[cl * 216];
#pragma unroll
        for (int di = 0; di < 3; ++di) {
#pragma unroll
            for (int dj = 0; dj < 3; ++dj) {
                int tap = di * 3 + dj;
                float xv0 = xr[di * 18 + dj];
                float xv1 = xr[di * 18 + dj + 8];
                const float4* wp = (const float4*)(wr + tap * 24);
                float4 w0 = wp[0], w1 = wp[1], w2 = wp[2], w3 = wp[3], w4 = wp[4];
                float w20 = wp[5].x;
                acc[0]  += xv0 * w0.x; acc[1]  += xv0 * w0.y; acc[2]  += xv0 * w0.z; acc[3]  += xv0 * w0.w;
                acc[4]  += xv0 * w1.x; acc[5]  += xv0 * w1.y; acc[6]  += xv0 * w1.z; acc[7]  += xv0 * w1.w;
                acc[8]  += xv0 * w2.x; acc[9]  += xv0 * w2.y; acc[10] += xv0 * w2.z; acc[11] += xv0 * w2.w;
                acc[12] += xv0 * w3.x; acc[13] += xv0 * w3.y; acc[14] += xv0 * w3.z; acc[15] += xv0 * w3.w;
                acc[16] += xv0 * w4.x; acc[17] += xv0 * w4.y; acc[18] += xv0 * w4.z; acc[19] += xv0 * w4.w;
                acc[20] += xv0 * w20;
                acc[21] += xv1 * w0.x; acc[22] += xv1 * w0.y; acc[23] += xv1 * w0.z; acc[24] += xv1 * w0.w;
                acc[25] += xv1 * w1.x; acc[26] += xv1 * w1.y; acc[27] += xv1 * w1.z; acc[28] += xv1 * w1.w;
                acc[29] += xv1 * w2.x; acc[30] += xv1 * w2.y; acc[31] += xv1 * w2.z; acc[32] += xv1 * w2.w;
                acc[33] += xv1 * w3.x; acc[34] += xv1 * w3.y; acc[35] += xv1 * w3.z; acc[36] += xv1 * w3.w;
                acc[37] += xv1 * w4.x; acc[38] += xv1 * w4.y; acc[39] += xv1 * w4.z; acc[40] += xv1 * w4.w;
                acc[41] += xv1 * w20;
            }
        }
    }
    // 3-round tree reduce over 8 waves (aliases sm; xs/wl dead)
    __syncthreads();
    if (wave >= 4) {
        float* red = &sm[((wave - 4) * 64 + lane) * 42];
#pragma unroll
        for (int o = 0; o < 42; ++o) red[o] = acc[o];
    }
    __syncthreads();
    if (wave < 4) {
        const float* red = &sm[(wave * 64 + lane) * 42];
#pragma unroll
        for (int o = 0; o < 42; ++o) acc[o] += red[o];
    }
    __syncthreads();
    if (wave == 2 || wave == 3) {
        float* red = &sm[((wave - 2) * 64 + lane) * 42];
#pragma unroll
        for (int o = 0; o < 42; ++o) red[o] = acc[o];
    }
    __syncthreads();
    if (wave < 2) {
        const float* red = &sm[(wave * 64 + lane) * 42];
#pragma unroll
        for (int o = 0; o < 42; ++o) acc[o] += red[o];
    }
    __syncthreads();
    if (wave == 1) {
        float* red = &sm[lane * 42];
#pragma unroll
        for (int o = 0; o < 42; ++o) red[o] = acc[o];
    }
    __syncthreads();
    if (wave == 0) {
        const float* red = &sm[lane * 42];
#pragma unroll
        for (int o = 0; o < 42; ++o) acc[o] += red[o];
        int i = i0 + pi;
        int ja = j0 + pj, jb = j0 + pj + 8;
#pragma unroll
        for (int o = 0; o < 18; ++o) {
            atomicAdd(&offw[((b * 18 + o) * HH + i) * WW + ja], acc[o]);
            atomicAdd(&offw[((b * 18 + o) * HH + i) * WW + jb], acc[21 + o]);
        }
#pragma unroll
        for (int o = 0; o < 3; ++o) {
            atomicAdd(&adw[((b * 3 + o) * HH + i) * WW + ja], acc[18 + o]);
            atomicAdd(&adw[((b * 3 + o) * HH + i) * WW + jb], acc[39 + o]);
        }
    }
}

// ---------------- K2: sampling + MFMA GEMM — 512 thr / 8 waves, vector operand loads --
__global__ __launch_bounds__(512) void deform_kernel(
    const float* __restrict__ x, const float* __restrict__ offw,
    const float* __restrict__ adw, const float* __restrict__ pb,
    const float* __restrict__ ab, const __bf16* __restrict__ wbf,
    float* __restrict__ out)
{
    __shared__ __align__(16) __bf16 xoff[32 * ROWH];
    __shared__ int4   qidx[288];
    __shared__ float4 gwt[288];

    int tid = threadIdx.x;
    int gid0 = blockIdx.x * 32;
    int b  = gid0 / HWX;
    int r0 = gid0 - b * HWX;
    int i  = r0 / WW;
    int j0 = r0 % WW;

    if (tid < 288) {
        int t = tid;
        int px = t / 9, n = t % 9;
        int j = j0 + px;
        float offx = offw[((b * 18 + n) * HH + i) * WW + j] + pb[n];
        float offy = offw[((b * 18 + 9 + n) * HH + i) * WW + j] + pb[9 + n];
        float zad  = adw[((b * 3 + (n % 3)) * HH + i) * WW + j] + ab[n % 3];
        float ad   = 2.f * (1.f - 1.f / (1.f + expf(-zad)));
        float pnx = (float)(n / 3 - 1), pny = (float)(n % 3 - 1);
        float pxf = (float)(i + 1) + pnx * (1.f + ad) + offx;
        float pyf = (float)(j + 1) + pny * (1.f + ad) + offy;
        float flx = floorf(pxf), fly = floorf(pyf);
        float qltx = fminf(fmaxf(flx, 0.f), 97.f);
        float qlty = fminf(fmaxf(fly, 0.f), 97.f);
        float qrbx = fminf(fmaxf(flx + 1.f, 0.f), 97.f);
        float qrby = fminf(fmaxf(fly + 1.f, 0.f), 97.f);
        bool mx = (pxf < 1.f) || (pxf > 96.f);
        bool my = (pyf < 1.f) || (pyf > 96.f);
        float pxm = mx ? flx : pxf; pxm = fminf(fmaxf(pxm, 0.f), 97.f);
        float pym = my ? fly : pyf; pym = fminf(fmaxf(pym, 0.f), 97.f);
        float glt = (1.f + (qltx - pxm)) * (1.f + (qlty - pym));
        float grb = (1.f - (qrbx - pxm)) * (1.f - (qrby - pym));
        float glb = (1.f + (qltx - pxm)) * (1.f - (qrby - pym));
        float grt = (1.f - (qrbx - pxm)) * (1.f + (qlty - pym));
        qidx[t] = make_int4((int)qltx, (int)qlty, (int)qrbx, (int)qrby);
        gwt[t]  = make_float4(glt, grb, glb, grt);
    }
    __syncthreads();

    int wv = tid >> 6, lane = tid & 63;
    int quad = lane >> 4, l15 = lane & 15;
    int mt = wv & 1;                 // m-tile: rows mt*16 .. mt*16+15
    int nh = wv >> 1;                // n-half: o range nh*32
    int o0 = nh * 32 + l15;
    int o1 = nh * 32 + 16 + l15;
    floatx4 acc0 = {0,0,0,0}, acc1 = {0,0,0,0};
    const __bf16* w0b = wbf + (size_t)o0 * KTOT;
    const __bf16* w1b = wbf + (size_t)o1 * KTOT;
    const float* xb = x + (size_t)b * CC * HWX;
    const __bf16* arow = &xoff[(mt * 16 + l15) * ROWH];

    for (int h = 0; h < 2; ++h) {
        for (int t = tid; t < 32 * KHALF; t += 512) {
            int px = t & 31;
            int rest = t >> 5;
            int n  = rest >> 6;
            int cl = rest & 63;
            int pidx = px * 9 + n;
            int4 q = qidx[pidx];
            float4 g = gwt[pidx];
            const float* xc = xb + (size_t)(h * 64 + cl) * HWX;
            bool rx_lt = (q.x >= 1) & (q.x <= 96);
            bool rx_rb = (q.z >= 1) & (q.z <= 96);
            bool cy_lt = (q.y >= 1) & (q.y <= 96);
            bool cy_rb = (q.w >= 1) & (q.w <= 96);
            float vlt = (rx_lt && cy_lt) ? xc[(q.x - 1) * WW + (q.y - 1)] : 0.f;
            float vrb = (rx_rb && cy_rb) ? xc[(q.z - 1) * WW + (q.w - 1)] : 0.f;
            float vlb = (rx_lt && cy_rb) ? xc[(q.x - 1) * WW + (q.w - 1)] : 0.f;
            float vrt = (rx_rb && cy_lt) ? xc[(q.z - 1) * WW + (q.y - 1)] : 0.f;
            float val = g.x * vlt + g.y * vrb + g.z * vlb + g.w * vrt;
            xoff[px * ROWH + cl * 9 + n] = (__bf16)val;
        }
        __syncthreads();

        for (int kt = 0; kt < 18; ++kt) {
            int kl = kt * 32 + quad * 8;
            int kg = h * KHALF + kl;
            bf16x8 a0 = *(const bf16x8*)(arow + kl);     // vector LDS reads (r7-verified)
            bf16x8 b0 = *(const bf16x8*)(w0b + kg);      // vector global loads (r7-verified)
            bf16x8 b1 = *(const bf16x8*)(w1b + kg);
            acc0 = __builtin_amdgcn_mfma_f32_16x16x32_bf16(a0, b0, acc0, 0, 0, 0);
            acc1 = __builtin_amdgcn_mfma_f32_16x16x32_bf16(a0, b1, acc1, 0, 0, 0);
        }
        __syncthreads();
    }

#pragma unroll
    for (int rr = 0; rr < 4; ++rr) {
        int m = mt * 16 + quad * 4 + rr;       // D row (verified)
        int j = j0 + m;
        out[((b * OC + o0) * HH + i) * WW + j] = acc0[rr];
        out[((b * OC + o1) * HH + i) * WW + j] = acc1[rr];
    }
}

extern "C" void kernel_launch(void* const* d_in, const int* in_sizes, int n_in,
                              void* d_out, int out_size, void* d_ws, size_t ws_size,
                              hipStream_t stream)
{
    const float* x  = (const float*)d_in[0];
    const float* cw = (const float*)d_in[1];
    const float* pw = (const float*)d_in[2];
    const float* pb = (const float*)d_in[3];
    const float* aw = (const float*)d_in[4];
    const float* ab = (const float*)d_in[5];
    float* out = (float*)d_out;

    char* ws = (char*)d_ws;
    float*  offw = (float*)ws;                      // 331776 fp32 raw sums (+adw contig)
    float*  adw  = offw + BB * 18 * HWX;            // 55296 fp32
    float*  wrep = adw + BB * 3 * HWX;              // 27648 fp32
    __bf16* wbf  = (__bf16*)(wrep + NWREP);         // 147456 bf16 (16B-aligned offset)

    int nprep = NZERO + NWREP + NWBF;
    prep_kernel<<<(nprep + 255) / 256, 256, 0, stream>>>(cw, pw, aw, offw, wrep, wbf);
    offsets_kernel<<<BB * 72 * 4, 512, 0, stream>>>(x, wrep, offw, adw);
    deform_kernel<<<(BB * HWX) / 32, 512, 0, stream>>>(x, offw, adw, pb, ab, wbf, out);
}

// Round 9
// 212.119 us; speedup vs baseline: 1.0788x; 1.0788x over previous
//
#include <hip/hip_runtime.h>
#include <hip/hip_bf16.h>
#include <math.h>

#define BB 2
#define CC 128
#define HH 96
#define WW 96
#define HWX (HH*WW)        // 9216
#define KTOT (CC*9)        // 1152
#define OC 128
#define KHALF 576          // deform K split: 64 channels per half
#define ROWH 600           // 576 + 24 pad; 1200 B row stride

#define NWREP (KTOT*24)    // 27648
#define NWBF  (KTOT*OC)    // 147456

typedef __attribute__((ext_vector_type(8))) __bf16 bf16x8;
typedef __attribute__((ext_vector_type(4))) float floatx4;

// ---------------- K0: prep — wrep repack + conv_w->bf16 (no zeroing needed) -----------
__global__ __launch_bounds__(256) void prep_kernel(const float* __restrict__ cw,
                                                   const float* __restrict__ pw,
                                                   const float* __restrict__ aw,
                                                   float* __restrict__ wrep,
                                                   __bf16* __restrict__ wbf)
{
    int t = blockIdx.x * 256 + threadIdx.x;
    if (t < NWREP) {
        int tapch = t / 24;
        int o = t - tapch * 24;
        float v = 0.f;
        if (o < 18)      v = pw[o * KTOT + tapch];
        else if (o < 21) v = aw[(o - 18) * KTOT + tapch];
        wrep[t] = v;
    } else if (t < NWREP + NWBF) {
        int r = t - NWREP;
        wbf[r] = (__bf16)cw[r];
    }
}

// ---------------- K1: offsets conv — scalar (s_load) weights, direct stores -----------
// grid = BB*144 = 288 blocks, 512 thr = 8 waves x 16-c chunk; lane = pixel (8x8 tile).
// Weight addresses wave-uniform via readfirstlane => SMEM loads, zero VMEM in hot loop.
__global__ __launch_bounds__(512) void offsets_kernel(
    const float* __restrict__ x, const float* __restrict__ wrep,
    float* __restrict__ offw, float* __restrict__ adw)
{
    __shared__ float xs[12800];   // [c][10][10]; aliased as reduce buffer afterwards
    int blk = blockIdx.x;
    int b = blk / 144;
    int t2 = blk % 144;
    int ti = t2 / 12, tj = t2 % 12;
    int i0 = ti * 8, j0 = tj * 8;
    int tid = threadIdx.x;

    for (int idx = tid; idx < 12800; idx += 512) {
        int c = idx / 100; int r = idx % 100; int u = r / 10, v = r % 10;
        int gi = i0 + u - 1, gj = j0 + v - 1;
        float val = 0.f;
        if (gi >= 0 && gi < HH && gj >= 0 && gj < WW)
            val = x[((b * CC + c) * HH + gi) * WW + gj];
        xs[idx] = val;
    }
    __syncthreads();

    int wave = __builtin_amdgcn_readfirstlane(tid >> 6);   // provably wave-uniform
    int lane = tid & 63;
    int pi = lane >> 3, pj = lane & 7;
    float acc[21];
#pragma unroll
    for (int o = 0; o < 21; ++o) acc[o] = 0.f;

    for (int cc = 0; cc < 16; ++cc) {
        int c = wave * 16 + cc;                            // uniform
        const float* xr = &xs[c * 100 + pi * 10 + pj];
        const float* wc = wrep + c * 216;                  // uniform base -> s_load
#pragma unroll
        for (int di = 0; di < 3; ++di) {
            float xv0 = xr[di * 10 + 0];
            float xv1 = xr[di * 10 + 1];
            float xv2 = xr[di * 10 + 2];
#pragma unroll
            for (int dj = 0; dj < 3; ++dj) {
                float xv = (dj == 0) ? xv0 : (dj == 1) ? xv1 : xv2;
                const float* wr = wc + (di * 3 + dj) * 24; // uniform
#pragma unroll
                for (int o = 0; o < 21; ++o) acc[o] += xv * wr[o];
            }
        }
    }
    // tree reduce over 8 waves (alias xs; 7*64*21 = 9408 <= 12800)
    __syncthreads();
    if (wave > 0) {
        float* red = &xs[((wave - 1) * 64 + lane) * 21];
#pragma unroll
        for (int o = 0; o < 21; ++o) red[o] = acc[o];
    }
    __syncthreads();
    if (wave == 0) {
#pragma unroll
        for (int r = 0; r < 7; ++r) {
            const float* red = &xs[(r * 64 + lane) * 21];
#pragma unroll
            for (int o = 0; o < 21; ++o) acc[o] += red[o];
        }
        int i = i0 + pi, j = j0 + pj;
#pragma unroll
        for (int o = 0; o < 18; ++o)
            offw[((b * 18 + o) * HH + i) * WW + j] = acc[o];   // raw sums, direct store
#pragma unroll
        for (int o = 0; o < 3; ++o)
            adw[((b * 3 + o) * HH + i) * WW + j] = acc[18 + o];
    }
}

// ---------------- K2: sampling + MFMA GEMM — EXACT round-7 structure (112.5 µs) -------
__global__ __launch_bounds__(256) void deform_kernel(
    const float* __restrict__ x, const float* __restrict__ offw,
    const float* __restrict__ adw, const float* __restrict__ pb,
    const float* __restrict__ ab, const __bf16* __restrict__ wbf,
    float* __restrict__ out)
{
    __shared__ __align__(16) __bf16 xoff[32 * ROWH];
    __shared__ int4   qidx[288];
    __shared__ float4 gwt[288];

    int tid = threadIdx.x;
    int gid0 = blockIdx.x * 32;
    int b  = gid0 / HWX;
    int r0 = gid0 - b * HWX;
    int i  = r0 / WW;
    int j0 = r0 % WW;

    for (int t = tid; t < 288; t += 256) {
        int px = t / 9, n = t % 9;
        int j = j0 + px;
        float offx = offw[((b * 18 + n) * HH + i) * WW + j] + pb[n];
        float offy = offw[((b * 18 + 9 + n) * HH + i) * WW + j] + pb[9 + n];
        float zad  = adw[((b * 3 + (n % 3)) * HH + i) * WW + j] + ab[n % 3];
        float ad   = 2.f * (1.f - 1.f / (1.f + expf(-zad)));
        float pnx = (float)(n / 3 - 1), pny = (float)(n % 3 - 1);
        float pxf = (float)(i + 1) + pnx * (1.f + ad) + offx;
        float pyf = (float)(j + 1) + pny * (1.f + ad) + offy;
        float flx = floorf(pxf), fly = floorf(pyf);
        float qltx = fminf(fmaxf(flx, 0.f), 97.f);
        float qlty = fminf(fmaxf(fly, 0.f), 97.f);
        float qrbx = fminf(fmaxf(flx + 1.f, 0.f), 97.f);
        float qrby = fminf(fmaxf(fly + 1.f, 0.f), 97.f);
        bool mx = (pxf < 1.f) || (pxf > 96.f);
        bool my = (pyf < 1.f) || (pyf > 96.f);
        float pxm = mx ? flx : pxf; pxm = fminf(fmaxf(pxm, 0.f), 97.f);
        float pym = my ? fly : pyf; pym = fminf(fmaxf(pym, 0.f), 97.f);
        float glt = (1.f + (qltx - pxm)) * (1.f + (qlty - pym));
        float grb = (1.f - (qrbx - pxm)) * (1.f - (qrby - pym));
        float glb = (1.f + (qltx - pxm)) * (1.f - (qrby - pym));
        float grt = (1.f - (qrbx - pxm)) * (1.f + (qlty - pym));
        qidx[t] = make_int4((int)qltx, (int)qlty, (int)qrbx, (int)qrby);
        gwt[t]  = make_float4(glt, grb, glb, grt);
    }
    __syncthreads();

    int wv = tid >> 6, lane = tid & 63;
    int quad = lane >> 4, l15 = lane & 15;
    int o0 = wv * 32 + l15;
    int o1 = wv * 32 + 16 + l15;
    floatx4 acc00 = {0,0,0,0}, acc01 = {0,0,0,0};
    floatx4 acc10 = {0,0,0,0}, acc11 = {0,0,0,0};
    const __bf16* w0b = wbf + (size_t)o0 * KTOT;
    const __bf16* w1b = wbf + (size_t)o1 * KTOT;
    const float* xb = x + (size_t)b * CC * HWX;
    const __bf16* arow0 = &xoff[l15 * ROWH];
    const __bf16* arow1 = &xoff[(16 + l15) * ROWH];

    for (int h = 0; h < 2; ++h) {
        for (int t = tid; t < 32 * KHALF; t += 256) {
            int px = t & 31;
            int rest = t >> 5;
            int n  = rest >> 6;
            int cl = rest & 63;
            int pidx = px * 9 + n;
            int4 q = qidx[pidx];
            float4 g = gwt[pidx];
            const float* xc = xb + (size_t)(h * 64 + cl) * HWX;
            bool rx_lt = (q.x >= 1) & (q.x <= 96);
            bool rx_rb = (q.z >= 1) & (q.z <= 96);
            bool cy_lt = (q.y >= 1) & (q.y <= 96);
            bool cy_rb = (q.w >= 1) & (q.w <= 96);
            float vlt = (rx_lt && cy_lt) ? xc[(q.x - 1) * WW + (q.y - 1)] : 0.f;
            float vrb = (rx_rb && cy_rb) ? xc[(q.z - 1) * WW + (q.w - 1)] : 0.f;
            float vlb = (rx_lt && cy_rb) ? xc[(q.x - 1) * WW + (q.w - 1)] : 0.f;
            float vrt = (rx_rb && cy_lt) ? xc[(q.z - 1) * WW + (q.y - 1)] : 0.f;
            float val = g.x * vlt + g.y * vrb + g.z * vlb + g.w * vrt;
            xoff[px * ROWH + cl * 9 + n] = (__bf16)val;
        }
        __syncthreads();

        for (int kt = 0; kt < 18; ++kt) {
            int kl = kt * 32 + quad * 8;
            int kg = h * KHALF + kl;
            bf16x8 a0 = *(const bf16x8*)(arow0 + kl);     // vector LDS reads (verified)
            bf16x8 a1 = *(const bf16x8*)(arow1 + kl);
            bf16x8 b0 = *(const bf16x8*)(w0b + kg);       // vector global loads (verified)
            bf16x8 b1 = *(const bf16x8*)(w1b + kg);
            acc00 = __builtin_amdgcn_mfma_f32_16x16x32_bf16(a0, b0, acc00, 0, 0, 0);
            acc01 = __builtin_amdgcn_mfma_f32_16x16x32_bf16(a0, b1, acc01, 0, 0, 0);
            acc10 = __builtin_amdgcn_mfma_f32_16x16x32_bf16(a1, b0, acc10, 0, 0, 0);
            acc11 = __builtin_amdgcn_mfma_f32_16x16x32_bf16(a1, b1, acc11, 0, 0, 0);
        }
        __syncthreads();
    }

#pragma unroll
    for (int rr = 0; rr < 4; ++rr) {
        int m0 = quad * 4 + rr;
        int ja = j0 + m0, jb = j0 + 16 + m0;
        out[((b * OC + o0) * HH + i) * WW + ja] = acc00[rr];
        out[((b * OC + o1) * HH + i) * WW + ja] = acc01[rr];
        out[((b * OC + o0) * HH + i) * WW + jb] = acc10[rr];
        out[((b * OC + o1) * HH + i) * WW + jb] = acc11[rr];
    }
}

extern "C" void kernel_launch(void* const* d_in, const int* in_sizes, int n_in,
                              void* d_out, int out_size, void* d_ws, size_t ws_size,
                              hipStream_t stream)
{
    const float* x  = (const float*)d_in[0];
    const float* cw = (const float*)d_in[1];
    const float* pw = (const float*)d_in[2];
    const float* pb = (const float*)d_in[3];
    const float* aw = (const float*)d_in[4];
    const float* ab = (const float*)d_in[5];
    float* out = (float*)d_out;

    char* ws = (char*)d_ws;
    float*  offw = (float*)ws;                      // 331776 fp32 raw sums
    float*  adw  = offw + BB * 18 * HWX;            // 55296 fp32 raw sums
    float*  wrep = adw + BB * 3 * HWX;              // 27648 fp32
    __bf16* wbf  = (__bf16*)(wrep + NWREP);         // 147456 bf16 (16B-aligned offset)

    int nprep = NWREP + NWBF;
    prep_kernel<<<(nprep + 255) / 256, 256, 0, stream>>>(cw, pw, aw, wrep, wbf);
    offsets_kernel<<<BB * 144, 512, 0, stream>>>(x, wrep, offw, adw);
    deform_kernel<<<(BB * HWX) / 32, 256, 0, stream>>>(x, offw, adw, pb, ab, wbf, out);
}